// Round 15
// baseline (107.541 us; speedup 1.0000x reference)
//
#include <hip/hip_runtime.h>
#include <hip/hip_bf16.h>
#include <cstdint>

// MultiRelationalGraphDiffusion: out = LeakyReLU( sum_k conv_w[k] * (adj_norm^k @ (h@W^T)) + conv_b )
// B=8, N=2048, D=256, K=4.
//
// Round-15 = R14 diffuse (best, 101.8us) + FUSED pre-pass:
//  - k_prepW: W -> Whi/Wlo bf16 (bf16x3 split), B-frag-major (frag = 1KB, lane il =
//    (o&15)+16*koctet). Tiny (~2us), makes htrans LDS-FREE.
//  - k_pre (1024 thr): bid<64 -> htrans: 16 waves x (32n x 128o) tiles, A-frags read
//    DIRECT from h (8 contig f32/lane, split in-reg), B-frags direct from Whi/Wlo
//    (coalesced 16B/lane, W L2-resident). ZERO LDS -> no R3 occupancy trap.
//    bid>=64 -> normadj (R10-14 proven code): htrans's ~10us hides under normadj's
//    27us HBM stream instead of serializing (~40us -> ~29us).
//  - diffuse x3: R14 exact (frag-major LDS, counted vmcnt, batch-per-XCD, setprio).
// Scales: adjS=256*adj_norm, cS=16*c -> acc=4096*(adj@c); next cS=acc/256; last tap acc/4096.

#define BATCH 8
#define NN    2048
#define DD    256
#define REPS  1e-9f
#define SLOPE 0.2f

typedef __bf16 bf16x8_t __attribute__((ext_vector_type(8)));
typedef __bf16 bf16x4_t __attribute__((ext_vector_type(4)));
typedef float  f32x4_t  __attribute__((ext_vector_type(4)));

__device__ __forceinline__ void gl2lds16(const void* g, void* l) {
    __builtin_amdgcn_global_load_lds(
        (const __attribute__((address_space(1))) unsigned int*)(uintptr_t)g,
        (__attribute__((address_space(3))) unsigned int*)(unsigned int)(uintptr_t)l,
        16, 0, 0);
}

__device__ __forceinline__ unsigned int pk_fp8x4(float a, float b, float c, float d) {
    int lo = __builtin_amdgcn_cvt_pk_fp8_f32(a, b, 0, false);
    return (unsigned int)__builtin_amdgcn_cvt_pk_fp8_f32(c, d, lo, true);
}

__device__ __forceinline__ f32x4_t cvt_f32_fp8x4(unsigned int u) {
    f32x4_t r;
    r[0] = __builtin_amdgcn_cvt_f32_fp8(u, 0);
    r[1] = __builtin_amdgcn_cvt_f32_fp8(u, 1);
    r[2] = __builtin_amdgcn_cvt_f32_fp8(u, 2);
    r[3] = __builtin_amdgcn_cvt_f32_fp8(u, 3);
    return r;
}

__device__ __forceinline__ uint2 q8(f32x4_t a, f32x4_t b, float sc) {
    uint2 r;
    r.x = pk_fp8x4(a[0] * sc, a[1] * sc, a[2] * sc, a[3] * sc);
    r.y = pk_fp8x4(b[0] * sc, b[1] * sc, b[2] * sc, b[3] * sc);
    return r;
}

// c-frag address (verified R10-R14)
__device__ __forceinline__ size_t cfrag_addr(int b, int row0, int col) {
    return ((size_t)(b * 64 + (row0 >> 5)) * 16 + (col >> 4)) * 512
         + ((col & 15) + 16 * ((row0 >> 3) & 3)) * 8 + (row0 & 4);
}

// hi/lo bf16 split of 8 consecutive f32
__device__ __forceinline__ void split8(const f32x4_t v0, const f32x4_t v1,
                                       bf16x8_t& hi, bf16x8_t& lo) {
#pragma unroll
    for (int e = 0; e < 4; ++e) {
        float x = v0[e]; __bf16 hh = (__bf16)x; hi[e] = hh; lo[e] = (__bf16)(x - (float)hh);
        float y = v1[e]; __bf16 hy = (__bf16)y; hi[e + 4] = hy; lo[e + 4] = (__bf16)(y - (float)hy);
    }
}

// ================= prepW: W -> Whi/Wlo bf16, B-frag-major (frag=1KB, 128 frags) =================
// frag f = (k>>5)*16 + (o>>4); lane il = (o&15) + 16*((k>>3)&3) holds W[o][k..k+8)
__global__ __launch_bounds__(256) void k_prepW(const float* __restrict__ W,
                                               __bf16* __restrict__ Whi,
                                               __bf16* __restrict__ Wlo) {
    const int t = blockIdx.x * 256 + threadIdx.x;   // 8192 threads
    const int o = t >> 5, k0 = (t & 31) * 8;
    f32x4_t v0 = *(const f32x4_t*)(W + (size_t)o * DD + k0);
    f32x4_t v1 = *(const f32x4_t*)(W + (size_t)o * DD + k0 + 4);
    bf16x8_t hi, lo;
    split8(v0, v1, hi, lo);
    const int f  = (k0 >> 5) * 16 + (o >> 4);
    const int il = (o & 15) + 16 * ((k0 >> 3) & 3);
    *(bf16x8_t*)(Whi + (size_t)f * 512 + il * 8) = hi;
    *(bf16x8_t*)(Wlo + (size_t)f * 512 + il * 8) = lo;
}

// ================= fused pre-pass: htrans (bid<64, LDS-free) + normadj (bid>=64) =================
__global__ __launch_bounds__(1024) void k_pre(const float* __restrict__ h,
                                              const __bf16* __restrict__ Whi,
                                              const __bf16* __restrict__ Wlo,
                                              const float* __restrict__ adj,
                                              _Float16* __restrict__ t_h,
                                              unsigned char* __restrict__ c0f,
                                              unsigned char* __restrict__ afrag) {
    __shared__ __align__(16) unsigned char fr[64 * 520];   // used by normadj branch only
    const int bid = blockIdx.x;
    const int tid = threadIdx.x;
    const int w = tid >> 6, l = tid & 63;

    if (bid < 64) {
        // ---------- htrans: wave = one 32n x 128o tile, K=256, bf16x3 MFMA ----------
        const int wt = bid * 16 + w;               // 1024 tiles
        const int b  = wt >> 7;
        const int r7 = wt & 127;
        const int n0 = (r7 >> 1) * 32;
        const int o0 = (r7 & 1) * 128;
        const int rl = l & 15, kq = l >> 4;

        f32x4_t acc[2][8];
#pragma unroll
        for (int i = 0; i < 2; ++i)
#pragma unroll
            for (int j = 0; j < 8; ++j) acc[i][j] = (f32x4_t){0.f, 0.f, 0.f, 0.f};

        for (int ks = 0; ks < 8; ++ks) {
            const int koff = ks * 32 + kq * 8;
            bf16x8_t ah[2], al[2];
#pragma unroll
            for (int i = 0; i < 2; ++i) {
                const float* ap = h + ((size_t)b * NN + n0 + i * 16 + rl) * DD + koff;
                split8(*(const f32x4_t*)ap, *(const f32x4_t*)(ap + 4), ah[i], al[i]);
            }
#pragma unroll
            for (int j = 0; j < 8; ++j) {
                const size_t fo = ((size_t)(ks * 16 + (o0 >> 4) + j)) * 512 + l * 8;
                bf16x8_t bh = *(const bf16x8_t*)(Whi + fo);
                bf16x8_t bl = *(const bf16x8_t*)(Wlo + fo);
#pragma unroll
                for (int i = 0; i < 2; ++i) {
                    acc[i][j] = __builtin_amdgcn_mfma_f32_16x16x32_bf16(ah[i], bh, acc[i][j], 0, 0, 0);
                    acc[i][j] = __builtin_amdgcn_mfma_f32_16x16x32_bf16(al[i], bh, acc[i][j], 0, 0, 0);
                    acc[i][j] = __builtin_amdgcn_mfma_f32_16x16x32_bf16(ah[i], bl, acc[i][j], 0, 0, 0);
                }
            }
        }

#pragma unroll
        for (int i = 0; i < 2; ++i)
#pragma unroll
            for (int j = 0; j < 8; ++j) {
                const int row0 = n0 + i * 16 + kq * 4;
                const int col  = o0 + j * 16 + rl;
                _Float16* tp = t_h + ((size_t)b * NN + row0) * DD + col;
#pragma unroll
                for (int r2 = 0; r2 < 4; ++r2) tp[r2 * DD] = (_Float16)acc[i][j][r2];
                *(unsigned int*)(c0f + cfrag_addr(b, row0, col)) =
                    pk_fp8x4(16.f * acc[i][j][0], 16.f * acc[i][j][1],
                             16.f * acc[i][j][2], 16.f * acc[i][j][3]);
            }
        return;
    }

    // ---------- normadj (verified R10-R14): 16 rows/block, frag-major via LDS ----------
    const int n = (bid - 64) * 16 + w;
    const float* src = adj + (size_t)n * NN;
    f32x4_t v[8];
#pragma unroll
    for (int q = 0; q < 4; ++q) {
        v[2 * q]     = *(const f32x4_t*)(src + q * 512 + l * 8);
        v[2 * q + 1] = *(const f32x4_t*)(src + q * 512 + l * 8 + 4);
    }
    float s = 0.f;
#pragma unroll
    for (int j = 0; j < 8; ++j) s += v[j][0] + v[j][1] + v[j][2] + v[j][3];
#pragma unroll
    for (int m = 1; m < 64; m <<= 1) s += __shfl_xor(s, m, 64);
    const float sc = 256.0f / (s + REPS);
#pragma unroll
    for (int q = 0; q < 4; ++q) {
        uint2 u = q8(v[2 * q], v[2 * q + 1], sc);
        *(uint2*)(fr + (16 * q + (l >> 2)) * 520 + w * 8 + (l & 3) * 128) = u;
    }
    __syncthreads();
    unsigned char* dst = afrag + (size_t)(bid - 64) * 64 * 512;
#pragma unroll
    for (int f2 = 0; f2 < 4; ++f2) {
        const int f = w * 4 + f2;
        *(uint2*)(dst + (size_t)f * 512 + l * 8) = *(const uint2*)(fr + f * 520 + l * 8);
    }
}

// ================= diffuse: R14 exact (frag-major LDS, counted vmcnt, b=p&7, setprio) =================
template <bool LAST>
__global__ __launch_bounds__(512) void k_diffuse(const unsigned char* __restrict__ afrag,
                                                 const unsigned char* __restrict__ cin,
                                                 unsigned char* __restrict__ cout,
                                                 const unsigned char* __restrict__ c1f,
                                                 const unsigned char* __restrict__ c2f,
                                                 const _Float16* __restrict__ t_h,
                                                 float* __restrict__ out,
                                                 const float* __restrict__ convw,
                                                 const float* __restrict__ convb) {
    __shared__ __align__(16) unsigned char As[3][8192];    // 24 KB
    __shared__ __align__(16) unsigned char Bs[3][16384];   // 48 KB

    const int tid = threadIdx.x;
    const int p = blockIdx.x;
    const int b  = p & 7;
    const int oh = (p >> 3) & 1;
    const int n0 = (p >> 4) * 64;

    const int lane = tid & 63, wv = tid >> 6;
    const int wr = wv >> 1, wc = wv & 1;
    const int rl = lane & 15, kq = lane >> 4;

    const unsigned char* aSrc = afrag
        + ((size_t)(b * 128 + (n0 >> 4) + wr) * 64) * 512 + (wv & 1) * 1024 + lane * 16;
    const unsigned char* cSrc = cin
        + ((size_t)(b * 64) * 16 + oh * 8) * 512 + (wv & 1) * 2048 + lane * 16;

    f32x4_t acc[4];
#pragma unroll
    for (int j = 0; j < 4; ++j) acc[j] = (f32x4_t){0.f, 0.f, 0.f, 0.f};

#define STAGE(T, BUF)                                                                  \
    {                                                                                  \
        const int tt = (T) & 15;                                                       \
        gl2lds16(aSrc + (size_t)tt * 2048, As[BUF] + wr * 2048 + (wv & 1) * 1024);     \
        const unsigned char* cs = cSrc + (size_t)(tt * 4 + wr) * 8192;                 \
        gl2lds16(cs, Bs[BUF] + wr * 4096 + (wv & 1) * 2048);                           \
        gl2lds16(cs + 1024, Bs[BUF] + wr * 4096 + (wv & 1) * 2048 + 1024);             \
    }

    STAGE(0, 0)
    STAGE(1, 1)

    int bc = 0, bs = 2;
    for (int t = 0; t < 16; ++t) {
        asm volatile("s_waitcnt vmcnt(3)" ::: "memory");
        __builtin_amdgcn_s_barrier();
        __builtin_amdgcn_sched_barrier(0);
        STAGE(t + 2, bs)
        __builtin_amdgcn_sched_barrier(0);
        const unsigned char* Ac = As[bc];
        const unsigned char* Bc = Bs[bc];
        __builtin_amdgcn_s_setprio(1);
#pragma unroll
        for (int s = 0; s < 4; ++s) {
            long a = *(const long*)(Ac + (wr * 4 + s) * 512 + lane * 8);
            long bb[4];
#pragma unroll
            for (int j = 0; j < 4; ++j)
                bb[j] = *(const long*)(Bc + (s * 8 + wc * 4 + j) * 512 + lane * 8);
#pragma unroll
            for (int j = 0; j < 4; ++j)
                acc[j] = __builtin_amdgcn_mfma_f32_16x16x32_fp8_fp8(a, bb[j], acc[j], 0, 0, 0);
        }
        __builtin_amdgcn_s_setprio(0);
        bc = (bc == 2) ? 0 : bc + 1;
        bs = (bs == 2) ? 0 : bs + 1;
    }
#undef STAGE

#pragma unroll
    for (int j = 0; j < 4; ++j) {
        const int row0 = n0 + wr * 16 + kq * 4;
        const int col  = oh * 128 + wc * 64 + j * 16 + rl;
        if (LAST) {
            const float cw0 = convw[0], cw1 = convw[1], cw2 = convw[2], cw3 = convw[3];
            const float cb  = convb[0];
            const float ru = 1.0f / 16.0f, rf = 1.0f / 4096.0f;
            float* op = out + ((size_t)b * NN + row0) * DD + col;
            const _Float16* tp = t_h + ((size_t)b * NN + row0) * DD + col;
            const size_t sa = cfrag_addr(b, row0, col);
            f32x4_t u1 = cvt_f32_fp8x4(*(const unsigned int*)(c1f + sa));
            f32x4_t u2 = cvt_f32_fp8x4(*(const unsigned int*)(c2f + sa));
#pragma unroll
            for (int r2 = 0; r2 < 4; ++r2) {
                float v = cw0 * (float)tp[r2 * DD] + cw1 * ru * u1[r2] + cw2 * ru * u2[r2]
                        + cw3 * rf * acc[j][r2] + cb;
                op[r2 * DD] = v >= 0.0f ? v : SLOPE * v;
            }
        } else {
            const float rs = 1.0f / 256.0f;
            *(unsigned int*)(cout + cfrag_addr(b, row0, col)) =
                pk_fp8x4(rs * acc[j][0], rs * acc[j][1], rs * acc[j][2], rs * acc[j][3]);
        }
    }
}

extern "C" void kernel_launch(void* const* d_in, const int* in_sizes, int n_in,
                              void* d_out, int out_size, void* d_ws, size_t ws_size,
                              hipStream_t stream) {
    const float* h   = (const float*)d_in[0];
    const float* adj = (const float*)d_in[1];
    const float* W   = (const float*)d_in[2];
    const float* cw  = (const float*)d_in[3];
    const float* cb  = (const float*)d_in[4];
    float* out = (float*)d_out;

    char* ws = (char*)d_ws;
    unsigned char* afrag = (unsigned char*)ws;                        // 32 MB
    unsigned char* c0f   = (unsigned char*)(ws + 33554432);           // 4 MB
    unsigned char* c1f   = (unsigned char*)(ws + 37748736);           // 4 MB
    unsigned char* c2f   = (unsigned char*)(ws + 41943040);           // 4 MB
    _Float16*      t_h   = (_Float16*)(ws + 46137344);                // 8.4 MB
    __bf16*        Whi   = (__bf16*)(ws + 54525952);                  // 128 KB
    __bf16*        Wlo   = (__bf16*)(ws + 54525952 + 131072);         // 128 KB (~54.8 MB)

    k_prepW<<<32, 256, 0, stream>>>(W, Whi, Wlo);
    k_pre<<<64 + BATCH * NN / 16, 1024, 0, stream>>>(h, Whi, Wlo, adj, t_h, c0f, afrag);
    k_diffuse<false><<<512, 512, 0, stream>>>(afrag, c0f, c1f, nullptr, nullptr, nullptr, out, cw, cb);
    k_diffuse<false><<<512, 512, 0, stream>>>(afrag, c1f, c2f, nullptr, nullptr, nullptr, out, cw, cb);
    k_diffuse<true ><<<512, 512, 0, stream>>>(afrag, c2f, nullptr, c1f, c2f, t_h, out, cw, cb);
}

// Round 16
// 96.025 us; speedup vs baseline: 1.1199x; 1.1199x over previous
//
#include <hip/hip_runtime.h>
#include <hip/hip_bf16.h>
#include <cstdint>

// MultiRelationalGraphDiffusion: out = LeakyReLU( sum_k conv_w[k] * (adj_norm^k @ (h@W^T)) + conv_b )
// B=8, N=2048, D=256, K=4.
//
// Round-16 = R14 diffuse (best) + fused pre-pass, REGISTER-LIGHT:
// R15 post-mortem: fused kernel's register allocation = max over branches; htrans's
// acc[2][8] (64 VGPR acc alone) pushed ALL blocks past the 64-VGPR occupancy cliff ->
// normadj at 4 waves/SIMD -> fusion lost. Fix:
//  - k_pre: __launch_bounds__(1024, 8) -> compiler must fit 8 waves/SIMD (<=64 VGPR).
//  - htrans branch: wave = 16n x 64o, acc[4] only (16 VGPR); 4096 waves = 256 blocks,
//    dispatched first. B-frags direct from Whi/Wlo (L2-resident), A direct from h.
//  - normadj branch (bid >= 256): R14 verbatim.
//  - diffuse x3: R14 exact. prepW: R15 exact.
// Scales: adjS=256*adj_norm, cS=16*c -> acc=4096*(adj@c); next cS=acc/256; last tap acc/4096.

#define BATCH 8
#define NN    2048
#define DD    256
#define REPS  1e-9f
#define SLOPE 0.2f

typedef __bf16 bf16x8_t __attribute__((ext_vector_type(8)));
typedef __bf16 bf16x4_t __attribute__((ext_vector_type(4)));
typedef float  f32x4_t  __attribute__((ext_vector_type(4)));

__device__ __forceinline__ void gl2lds16(const void* g, void* l) {
    __builtin_amdgcn_global_load_lds(
        (const __attribute__((address_space(1))) unsigned int*)(uintptr_t)g,
        (__attribute__((address_space(3))) unsigned int*)(unsigned int)(uintptr_t)l,
        16, 0, 0);
}

__device__ __forceinline__ unsigned int pk_fp8x4(float a, float b, float c, float d) {
    int lo = __builtin_amdgcn_cvt_pk_fp8_f32(a, b, 0, false);
    return (unsigned int)__builtin_amdgcn_cvt_pk_fp8_f32(c, d, lo, true);
}

__device__ __forceinline__ f32x4_t cvt_f32_fp8x4(unsigned int u) {
    f32x4_t r;
    r[0] = __builtin_amdgcn_cvt_f32_fp8(u, 0);
    r[1] = __builtin_amdgcn_cvt_f32_fp8(u, 1);
    r[2] = __builtin_amdgcn_cvt_f32_fp8(u, 2);
    r[3] = __builtin_amdgcn_cvt_f32_fp8(u, 3);
    return r;
}

__device__ __forceinline__ uint2 q8(f32x4_t a, f32x4_t b, float sc) {
    uint2 r;
    r.x = pk_fp8x4(a[0] * sc, a[1] * sc, a[2] * sc, a[3] * sc);
    r.y = pk_fp8x4(b[0] * sc, b[1] * sc, b[2] * sc, b[3] * sc);
    return r;
}

// c-frag address (verified R10-R15)
__device__ __forceinline__ size_t cfrag_addr(int b, int row0, int col) {
    return ((size_t)(b * 64 + (row0 >> 5)) * 16 + (col >> 4)) * 512
         + ((col & 15) + 16 * ((row0 >> 3) & 3)) * 8 + (row0 & 4);
}

// hi/lo bf16 split of 8 consecutive f32
__device__ __forceinline__ void split8(const f32x4_t v0, const f32x4_t v1,
                                       bf16x8_t& hi, bf16x8_t& lo) {
#pragma unroll
    for (int e = 0; e < 4; ++e) {
        float x = v0[e]; __bf16 hh = (__bf16)x; hi[e] = hh; lo[e] = (__bf16)(x - (float)hh);
        float y = v1[e]; __bf16 hy = (__bf16)y; hi[e + 4] = hy; lo[e + 4] = (__bf16)(y - (float)hy);
    }
}

// ================= prepW: W -> Whi/Wlo bf16, B-frag-major (verified R15) =================
__global__ __launch_bounds__(256) void k_prepW(const float* __restrict__ W,
                                               __bf16* __restrict__ Whi,
                                               __bf16* __restrict__ Wlo) {
    const int t = blockIdx.x * 256 + threadIdx.x;   // 8192 threads
    const int o = t >> 5, k0 = (t & 31) * 8;
    f32x4_t v0 = *(const f32x4_t*)(W + (size_t)o * DD + k0);
    f32x4_t v1 = *(const f32x4_t*)(W + (size_t)o * DD + k0 + 4);
    bf16x8_t hi, lo;
    split8(v0, v1, hi, lo);
    const int f  = (k0 >> 5) * 16 + (o >> 4);
    const int il = (o & 15) + 16 * ((k0 >> 3) & 3);
    *(bf16x8_t*)(Whi + (size_t)f * 512 + il * 8) = hi;
    *(bf16x8_t*)(Wlo + (size_t)f * 512 + il * 8) = lo;
}

// ============ fused pre-pass: htrans (bid<256, register-light) + normadj ============
__global__ __launch_bounds__(1024, 8) void k_pre(const float* __restrict__ h,
                                                 const __bf16* __restrict__ Whi,
                                                 const __bf16* __restrict__ Wlo,
                                                 const float* __restrict__ adj,
                                                 _Float16* __restrict__ t_h,
                                                 unsigned char* __restrict__ c0f,
                                                 unsigned char* __restrict__ afrag) {
    __shared__ __align__(16) unsigned char fr[64 * 520];   // normadj branch only (33 KB)
    const int bid = blockIdx.x;
    const int tid = threadIdx.x;
    const int w = tid >> 6, l = tid & 63;

    if (bid < 256) {
        // ---------- htrans: wave = one 16n x 64o tile, K=256, bf16x3 MFMA ----------
        const int wt = bid * 16 + w;               // 4096 wave-tiles
        const int b  = wt >> 9;                    // 512 tiles per batch
        const int r9 = wt & 511;
        const int n0 = (r9 >> 2) * 16;             // 128 n-tiles
        const int o0 = (r9 & 3) * 64;              // 4 o-tiles
        const int rl = l & 15, kq = l >> 4;

        f32x4_t acc[4];
#pragma unroll
        for (int j = 0; j < 4; ++j) acc[j] = (f32x4_t){0.f, 0.f, 0.f, 0.f};

        for (int ks = 0; ks < 8; ++ks) {
            const int koff = ks * 32 + kq * 8;
            bf16x8_t ah, al;
            {
                const float* ap = h + ((size_t)b * NN + n0 + rl) * DD + koff;
                split8(*(const f32x4_t*)ap, *(const f32x4_t*)(ap + 4), ah, al);
            }
#pragma unroll
            for (int j = 0; j < 4; ++j) {
                const size_t fo = ((size_t)(ks * 16 + (o0 >> 4) + j)) * 512 + l * 8;
                bf16x8_t bh = *(const bf16x8_t*)(Whi + fo);
                bf16x8_t bl = *(const bf16x8_t*)(Wlo + fo);
                acc[j] = __builtin_amdgcn_mfma_f32_16x16x32_bf16(ah, bh, acc[j], 0, 0, 0);
                acc[j] = __builtin_amdgcn_mfma_f32_16x16x32_bf16(al, bh, acc[j], 0, 0, 0);
                acc[j] = __builtin_amdgcn_mfma_f32_16x16x32_bf16(ah, bl, acc[j], 0, 0, 0);
            }
        }

#pragma unroll
        for (int j = 0; j < 4; ++j) {
            const int row0 = n0 + kq * 4;
            const int col  = o0 + j * 16 + rl;
            _Float16* tp = t_h + ((size_t)b * NN + row0) * DD + col;
#pragma unroll
            for (int r2 = 0; r2 < 4; ++r2) tp[r2 * DD] = (_Float16)acc[j][r2];
            *(unsigned int*)(c0f + cfrag_addr(b, row0, col)) =
                pk_fp8x4(16.f * acc[j][0], 16.f * acc[j][1],
                         16.f * acc[j][2], 16.f * acc[j][3]);
        }
        return;
    }

    // ---------- normadj (verified R10-R15): 16 rows/block, frag-major via LDS ----------
    const int n = (bid - 256) * 16 + w;
    const float* src = adj + (size_t)n * NN;
    f32x4_t v[8];
#pragma unroll
    for (int q = 0; q < 4; ++q) {
        v[2 * q]     = *(const f32x4_t*)(src + q * 512 + l * 8);
        v[2 * q + 1] = *(const f32x4_t*)(src + q * 512 + l * 8 + 4);
    }
    float s = 0.f;
#pragma unroll
    for (int j = 0; j < 8; ++j) s += v[j][0] + v[j][1] + v[j][2] + v[j][3];
#pragma unroll
    for (int m = 1; m < 64; m <<= 1) s += __shfl_xor(s, m, 64);
    const float sc = 256.0f / (s + REPS);
#pragma unroll
    for (int q = 0; q < 4; ++q) {
        uint2 u = q8(v[2 * q], v[2 * q + 1], sc);
        *(uint2*)(fr + (16 * q + (l >> 2)) * 520 + w * 8 + (l & 3) * 128) = u;
    }
    __syncthreads();
    unsigned char* dst = afrag + (size_t)(bid - 256) * 64 * 512;
#pragma unroll
    for (int f2 = 0; f2 < 4; ++f2) {
        const int f = w * 4 + f2;
        *(uint2*)(dst + (size_t)f * 512 + l * 8) = *(const uint2*)(fr + f * 520 + l * 8);
    }
}

// ================= diffuse: R14 exact (frag-major LDS, counted vmcnt, b=p&7, setprio) =================
template <bool LAST>
__global__ __launch_bounds__(512) void k_diffuse(const unsigned char* __restrict__ afrag,
                                                 const unsigned char* __restrict__ cin,
                                                 unsigned char* __restrict__ cout,
                                                 const unsigned char* __restrict__ c1f,
                                                 const unsigned char* __restrict__ c2f,
                                                 const _Float16* __restrict__ t_h,
                                                 float* __restrict__ out,
                                                 const float* __restrict__ convw,
                                                 const float* __restrict__ convb) {
    __shared__ __align__(16) unsigned char As[3][8192];    // 24 KB
    __shared__ __align__(16) unsigned char Bs[3][16384];   // 48 KB

    const int tid = threadIdx.x;
    const int p = blockIdx.x;
    const int b  = p & 7;
    const int oh = (p >> 3) & 1;
    const int n0 = (p >> 4) * 64;

    const int lane = tid & 63, wv = tid >> 6;
    const int wr = wv >> 1, wc = wv & 1;
    const int rl = lane & 15, kq = lane >> 4;

    const unsigned char* aSrc = afrag
        + ((size_t)(b * 128 + (n0 >> 4) + wr) * 64) * 512 + (wv & 1) * 1024 + lane * 16;
    const unsigned char* cSrc = cin
        + ((size_t)(b * 64) * 16 + oh * 8) * 512 + (wv & 1) * 2048 + lane * 16;

    f32x4_t acc[4];
#pragma unroll
    for (int j = 0; j < 4; ++j) acc[j] = (f32x4_t){0.f, 0.f, 0.f, 0.f};

#define STAGE(T, BUF)                                                                  \
    {                                                                                  \
        const int tt = (T) & 15;                                                       \
        gl2lds16(aSrc + (size_t)tt * 2048, As[BUF] + wr * 2048 + (wv & 1) * 1024);     \
        const unsigned char* cs = cSrc + (size_t)(tt * 4 + wr) * 8192;                 \
        gl2lds16(cs, Bs[BUF] + wr * 4096 + (wv & 1) * 2048);                           \
        gl2lds16(cs + 1024, Bs[BUF] + wr * 4096 + (wv & 1) * 2048 + 1024);             \
    }

    STAGE(0, 0)
    STAGE(1, 1)

    int bc = 0, bs = 2;
    for (int t = 0; t < 16; ++t) {
        asm volatile("s_waitcnt vmcnt(3)" ::: "memory");
        __builtin_amdgcn_s_barrier();
        __builtin_amdgcn_sched_barrier(0);
        STAGE(t + 2, bs)
        __builtin_amdgcn_sched_barrier(0);
        const unsigned char* Ac = As[bc];
        const unsigned char* Bc = Bs[bc];
        __builtin_amdgcn_s_setprio(1);
#pragma unroll
        for (int s = 0; s < 4; ++s) {
            long a = *(const long*)(Ac + (wr * 4 + s) * 512 + lane * 8);
            long bb[4];
#pragma unroll
            for (int j = 0; j < 4; ++j)
                bb[j] = *(const long*)(Bc + (s * 8 + wc * 4 + j) * 512 + lane * 8);
#pragma unroll
            for (int j = 0; j < 4; ++j)
                acc[j] = __builtin_amdgcn_mfma_f32_16x16x32_fp8_fp8(a, bb[j], acc[j], 0, 0, 0);
        }
        __builtin_amdgcn_s_setprio(0);
        bc = (bc == 2) ? 0 : bc + 1;
        bs = (bs == 2) ? 0 : bs + 1;
    }
#undef STAGE

#pragma unroll
    for (int j = 0; j < 4; ++j) {
        const int row0 = n0 + wr * 16 + kq * 4;
        const int col  = oh * 128 + wc * 64 + j * 16 + rl;
        if (LAST) {
            const float cw0 = convw[0], cw1 = convw[1], cw2 = convw[2], cw3 = convw[3];
            const float cb  = convb[0];
            const float ru = 1.0f / 16.0f, rf = 1.0f / 4096.0f;
            float* op = out + ((size_t)b * NN + row0) * DD + col;
            const _Float16* tp = t_h + ((size_t)b * NN + row0) * DD + col;
            const size_t sa = cfrag_addr(b, row0, col);
            f32x4_t u1 = cvt_f32_fp8x4(*(const unsigned int*)(c1f + sa));
            f32x4_t u2 = cvt_f32_fp8x4(*(const unsigned int*)(c2f + sa));
#pragma unroll
            for (int r2 = 0; r2 < 4; ++r2) {
                float v = cw0 * (float)tp[r2 * DD] + cw1 * ru * u1[r2] + cw2 * ru * u2[r2]
                        + cw3 * rf * acc[j][r2] + cb;
                op[r2 * DD] = v >= 0.0f ? v : SLOPE * v;
            }
        } else {
            const float rs = 1.0f / 256.0f;
            *(unsigned int*)(cout + cfrag_addr(b, row0, col)) =
                pk_fp8x4(rs * acc[j][0], rs * acc[j][1], rs * acc[j][2], rs * acc[j][3]);
        }
    }
}

extern "C" void kernel_launch(void* const* d_in, const int* in_sizes, int n_in,
                              void* d_out, int out_size, void* d_ws, size_t ws_size,
                              hipStream_t stream) {
    const float* h   = (const float*)d_in[0];
    const float* adj = (const float*)d_in[1];
    const float* W   = (const float*)d_in[2];
    const float* cw  = (const float*)d_in[3];
    const float* cb  = (const float*)d_in[4];
    float* out = (float*)d_out;

    char* ws = (char*)d_ws;
    unsigned char* afrag = (unsigned char*)ws;                        // 32 MB
    unsigned char* c0f   = (unsigned char*)(ws + 33554432);           // 4 MB
    unsigned char* c1f   = (unsigned char*)(ws + 37748736);           // 4 MB
    unsigned char* c2f   = (unsigned char*)(ws + 41943040);           // 4 MB
    _Float16*      t_h   = (_Float16*)(ws + 46137344);                // 8.4 MB
    __bf16*        Whi   = (__bf16*)(ws + 54525952);                  // 128 KB
    __bf16*        Wlo   = (__bf16*)(ws + 54525952 + 131072);         // 128 KB (~54.8 MB)

    k_prepW<<<32, 256, 0, stream>>>(W, Whi, Wlo);
    k_pre<<<256 + BATCH * NN / 16, 1024, 0, stream>>>(h, Whi, Wlo, adj, t_h, c0f, afrag);
    k_diffuse<false><<<512, 512, 0, stream>>>(afrag, c0f, c1f, nullptr, nullptr, nullptr, out, cw, cb);
    k_diffuse<false><<<512, 512, 0, stream>>>(afrag, c1f, c2f, nullptr, nullptr, nullptr, out, cw, cb);
    k_diffuse<true ><<<512, 512, 0, stream>>>(afrag, c2f, nullptr, c1f, c2f, t_h, out, cw, cb);
}